// Round 3
// baseline (778.024 us; speedup 1.0000x reference)
//
#include <hip/hip_runtime.h>
#include <hip/hip_bf16.h>
#include <cstdint>
#include <cstddef>

// Problem: B=1, T=4096, C=1024, NH=16, HD=64. fp32 I/O, bf16 internal compute.
// Pipeline: convert x -> bf16; transpose+convert Wqkv/Wproj -> B^T bf16;
//           GEMM1(+bias+RoPE, scatters Q/K head-major and V transposed)
//           -> flash attention -> GEMM2(+bias) -> fp32 out.
// Workspace footprint: 40 MiB total (Y aliases xb after gemm1).
constexpr int TSEQ = 4096;
constexpr int CDIM = 1024;
constexpr int NHEAD = 16;
constexpr int HDIM = 64;

using bf16 = __hip_bfloat16;
typedef __bf16 bf16x8 __attribute__((ext_vector_type(8)));
typedef float floatx4 __attribute__((ext_vector_type(4)));

// -------- elementwise fp32 -> bf16 (4 elems/thread) --------
__global__ __launch_bounds__(256) void f32_to_bf16(
    const float4* __restrict__ in, uint64_t* __restrict__ out, int n4) {
  const int i = blockIdx.x * 256 + threadIdx.x;
  if (i < n4) {
    const float4 v = in[i];
    union { bf16 h[4]; uint64_t u; } p;
    p.h[0] = __float2bfloat16(v.x);
    p.h[1] = __float2bfloat16(v.y);
    p.h[2] = __float2bfloat16(v.z);
    p.h[3] = __float2bfloat16(v.w);
    out[i] = p.u;
  }
}

// -------- transpose + convert (fp32 -> bf16), out[c][r] = in[r][c] --------
__global__ __launch_bounds__(256) void transpose_f32_bf16(
    const float* __restrict__ in, bf16* __restrict__ out, int R, int C) {
  __shared__ float tile[32][33];
  const int c0 = blockIdx.x * 32, r0 = blockIdx.y * 32;
  const int tx = threadIdx.x, ty = threadIdx.y;  // 32 x 8
#pragma unroll
  for (int i = 0; i < 32; i += 8)
    tile[ty + i][tx] = in[(size_t)(r0 + ty + i) * C + c0 + tx];
  __syncthreads();
#pragma unroll
  for (int i = 0; i < 32; i += 8)
    out[(size_t)(c0 + ty + i) * R + r0 + tx] = __float2bfloat16(tile[tx][ty + i]);
}

// -------- GEMM: C = A(MxK,bf16) * Bt(NxK,bf16)^T + bias(fp32) --------
// MODE 0: fp32 output to Cout[M][N].
// MODE 1: qkv epilogue: cols [0,1024)=q, [1024,2048)=k -> RoPE -> Qh/Kh[h][t][64];
//         cols [2048,3072)=v -> Vt[h][d][t] (direct transposed store).
template <int MODE>
__global__ __launch_bounds__(256) void gemm_bt(
    const bf16* __restrict__ A, const bf16* __restrict__ Bt,
    const float* __restrict__ bias, float* __restrict__ Cout,
    bf16* __restrict__ Qh, bf16* __restrict__ Kh, bf16* __restrict__ Vt,
    int M, int N, int K) {
  __shared__ bf16 As[128][40];  // stride 40 -> 2-way LDS aliasing only (free)
  __shared__ bf16 Bs[128][40];
  const int tid = threadIdx.x;
  const int m0 = blockIdx.y * 128, n0 = blockIdx.x * 128;
  const int wave = tid >> 6, lane = tid & 63;
  const int l15 = lane & 15, quad = lane >> 4;
  const int wm = (wave >> 1) * 64, wn = (wave & 1) * 64;

  const floatx4 fzero = {0.f, 0.f, 0.f, 0.f};
  floatx4 acc[4][4];
#pragma unroll
  for (int mi = 0; mi < 4; mi++)
#pragma unroll
    for (int ni = 0; ni < 4; ni++) acc[mi][ni] = fzero;

  const int row0 = tid >> 2;            // 0..63
  const int colb = (tid & 3) << 3;      // 0,8,16,24

  for (int k0 = 0; k0 < K; k0 += 32) {
    __syncthreads();
    *(float4*)(&As[row0][colb]) =
        *(const float4*)(A + (size_t)(m0 + row0) * K + k0 + colb);
    *(float4*)(&As[row0 + 64][colb]) =
        *(const float4*)(A + (size_t)(m0 + row0 + 64) * K + k0 + colb);
    *(float4*)(&Bs[row0][colb]) =
        *(const float4*)(Bt + (size_t)(n0 + row0) * K + k0 + colb);
    *(float4*)(&Bs[row0 + 64][colb]) =
        *(const float4*)(Bt + (size_t)(n0 + row0 + 64) * K + k0 + colb);
    __syncthreads();

    bf16x8 a[4], b[4];
#pragma unroll
    for (int mi = 0; mi < 4; mi++)
      a[mi] = *(const bf16x8*)(&As[wm + mi * 16 + l15][quad * 8]);
#pragma unroll
    for (int ni = 0; ni < 4; ni++)
      b[ni] = *(const bf16x8*)(&Bs[wn + ni * 16 + l15][quad * 8]);
#pragma unroll
    for (int mi = 0; mi < 4; mi++)
#pragma unroll
      for (int ni = 0; ni < 4; ni++)
        acc[mi][ni] = __builtin_amdgcn_mfma_f32_16x16x32_bf16(
            a[mi], b[ni], acc[mi][ni], 0, 0, 0);
  }

  // Epilogue. C/D layout: col = lane&15, row = quad*4 + reg.
#pragma unroll
  for (int ni = 0; ni < 4; ni++) {
    const int col = n0 + wn + ni * 16 + l15;
    const float bv = bias[col];
    if (MODE == 1) {
      const int sec = col >> 10;        // 0=q 1=k 2=v (uniform per wave)
      const int cd = col & 1023;
      const int hh = cd >> 6, d = cd & 63;
      if (sec == 2) {
        // V: direct transposed store Vt[h][d][t], 4 consecutive t packed (8B)
#pragma unroll
        for (int mi = 0; mi < 4; mi++) {
          const int t0 = m0 + wm + mi * 16 + quad * 4;
          union { bf16 h[4]; uint64_t u; } p;
#pragma unroll
          for (int r = 0; r < 4; r++)
            p.h[r] = __float2bfloat16(acc[mi][ni][r] + bv);
          *(uint64_t*)(Vt + ((size_t)hh * HDIM + d) * TSEQ + t0) = p.u;
        }
      } else {
        // inv_freq[d%32] = 10000^(-2*(d%32)/64)
        const float invf =
            exp2f((float)(d & 31) * (-2.0f / 64.0f) * 13.287712379549449f);
        bf16* dst = (sec == 0) ? Qh : Kh;
#pragma unroll
        for (int mi = 0; mi < 4; mi++) {
#pragma unroll
          for (int r = 0; r < 4; r++) {
            const int row = m0 + wm + mi * 16 + quad * 4 + r;  // t
            const float v = acc[mi][ni][r] + bv;
            // pair partner (col^1) lives in lane^1
            const float partner = __shfl_xor(v, 1, 64);
            float sn, cs;
            sincosf((float)row * invf, &sn, &cs);
            const float res = v * cs + ((d & 1) ? partner : -partner) * sn;
            dst[((size_t)hh * TSEQ + row) * HDIM + d] = __float2bfloat16(res);
          }
        }
      }
    } else {
#pragma unroll
      for (int mi = 0; mi < 4; mi++) {
#pragma unroll
        for (int r = 0; r < 4; r++) {
          const int row = m0 + wm + mi * 16 + quad * 4 + r;
          Cout[(size_t)row * N + col] = acc[mi][ni][r] + bv;
        }
      }
    }
  }
}

// -------- flash attention --------
// grid (T/128, NHEAD), 256 threads = 4 waves, wave w owns 32 q-rows.
__global__ __launch_bounds__(256) void attn_kernel(
    const bf16* __restrict__ Qh, const bf16* __restrict__ Kh,
    const bf16* __restrict__ Vt, bf16* __restrict__ Y) {
  const int h = blockIdx.y;
  const int qb = gridDim.x - 1 - blockIdx.x;  // heavy blocks first
  const int q0 = qb * 128;
  const int tid = threadIdx.x;
  const int w = tid >> 6, lane = tid & 63;
  const int l15 = lane & 15, quad = lane >> 4;
  const bf16* Qb = Qh + (size_t)h * TSEQ * HDIM;
  const bf16* Kb = Kh + (size_t)h * TSEQ * HDIM;
  const bf16* Vb = Vt + (size_t)h * HDIM * TSEQ;

  __shared__ bf16 Plds[4][32][72];  // per-wave P round-trip (C->A layout)

  // Q fragments: A-layout m=lane&15, k=quad*8+j (+32*ks)
  bf16x8 qf[2][2];
#pragma unroll
  for (int mi = 0; mi < 2; mi++)
#pragma unroll
    for (int ks = 0; ks < 2; ks++)
      qf[mi][ks] = *(const bf16x8*)(Qb +
          (size_t)(q0 + w * 32 + mi * 16 + l15) * HDIM + ks * 32 + quad * 8);

  const floatx4 fzero = {0.f, 0.f, 0.f, 0.f};
  floatx4 o[2][4];
  float m_i[2][4], l_i[2][4];
#pragma unroll
  for (int mi = 0; mi < 2; mi++) {
#pragma unroll
    for (int nd = 0; nd < 4; nd++) o[mi][nd] = fzero;
#pragma unroll
    for (int r = 0; r < 4; r++) { m_i[mi][r] = -1e30f; l_i[mi][r] = 0.f; }
  }

  const int nkv = (q0 >> 6) + 2;
  const float sc = 0.125f * 1.4426950408889634f;  // 1/sqrt(64) * log2(e)

  for (int kb = 0; kb < nkv; kb++) {
    const int kv0 = kb * 64;
    floatx4 s[2][4];
#pragma unroll
    for (int mi = 0; mi < 2; mi++)
#pragma unroll
      for (int ni = 0; ni < 4; ni++) s[mi][ni] = fzero;

#pragma unroll
    for (int ni = 0; ni < 4; ni++) {
#pragma unroll
      for (int ks = 0; ks < 2; ks++) {
        const bf16x8 kf = *(const bf16x8*)(Kb +
            (size_t)(kv0 + ni * 16 + l15) * HDIM + ks * 32 + quad * 8);
#pragma unroll
        for (int mi = 0; mi < 2; mi++)
          s[mi][ni] = __builtin_amdgcn_mfma_f32_16x16x32_bf16(
              qf[mi][ks], kf, s[mi][ni], 0, 0, 0);
      }
    }

    // online softmax; lane owns rows quad*4+r, cols kv0+ni*16+l15
#pragma unroll
    for (int mi = 0; mi < 2; mi++) {
#pragma unroll
      for (int r = 0; r < 4; r++) {
        const int qrow = q0 + w * 32 + mi * 16 + quad * 4 + r;
        float rowmax = -1e30f;
#pragma unroll
        for (int ni = 0; ni < 4; ni++) {
          const int col = kv0 + ni * 16 + l15;
          const float v = (col <= qrow) ? s[mi][ni][r] * sc : -1e30f;
          s[mi][ni][r] = v;
          rowmax = fmaxf(rowmax, v);
        }
#pragma unroll
        for (int off = 1; off < 16; off <<= 1)
          rowmax = fmaxf(rowmax, __shfl_xor(rowmax, off, 64));
        const float mnew = fmaxf(m_i[mi][r], rowmax);
        const float alpha = exp2f(m_i[mi][r] - mnew);
        m_i[mi][r] = mnew;
        float rsum = 0.f;
#pragma unroll
        for (int ni = 0; ni < 4; ni++) {
          const float p = exp2f(s[mi][ni][r] - mnew);
          s[mi][ni][r] = p;
          rsum += p;
        }
#pragma unroll
        for (int off = 1; off < 16; off <<= 1)
          rsum += __shfl_xor(rsum, off, 64);
        l_i[mi][r] = l_i[mi][r] * alpha + rsum;
#pragma unroll
        for (int nd = 0; nd < 4; nd++) o[mi][nd][r] *= alpha;
      }
    }

    // P: C-layout -> LDS -> A-layout (same-wave DS ops are in-order; m120)
#pragma unroll
    for (int mi = 0; mi < 2; mi++)
#pragma unroll
      for (int ni = 0; ni < 4; ni++)
#pragma unroll
        for (int r = 0; r < 4; r++)
          Plds[w][mi * 16 + quad * 4 + r][ni * 16 + l15] =
              __float2bfloat16(s[mi][ni][r]);
    __asm__ __volatile__("" ::: "memory");  // keep compiler from reordering

#pragma unroll
    for (int ks = 0; ks < 2; ks++) {
      bf16x8 pa[2];
#pragma unroll
      for (int mi = 0; mi < 2; mi++)
        pa[mi] = *(const bf16x8*)(&Plds[w][mi * 16 + l15][ks * 32 + quad * 8]);
#pragma unroll
      for (int nd = 0; nd < 4; nd++) {
        const bf16x8 vf = *(const bf16x8*)(Vb +
            (size_t)(nd * 16 + l15) * TSEQ + kv0 + ks * 32 + quad * 8);
#pragma unroll
        for (int mi = 0; mi < 2; mi++)
          o[mi][nd] = __builtin_amdgcn_mfma_f32_16x16x32_bf16(
              pa[mi], vf, o[mi][nd], 0, 0, 0);
      }
    }
  }

  // epilogue: divide by l, write Y[t][h*64+d] (bf16)
#pragma unroll
  for (int mi = 0; mi < 2; mi++) {
#pragma unroll
    for (int nd = 0; nd < 4; nd++) {
#pragma unroll
      for (int r = 0; r < 4; r++) {
        const int t = q0 + w * 32 + mi * 16 + quad * 4 + r;
        const int d = nd * 16 + l15;
        Y[(size_t)t * CDIM + h * HDIM + d] =
            __float2bfloat16(o[mi][nd][r] / l_i[mi][r]);
      }
    }
  }
}

extern "C" void kernel_launch(void* const* d_in, const int* in_sizes, int n_in,
                              void* d_out, int out_size, void* d_ws,
                              size_t ws_size, hipStream_t stream) {
  const float* x     = (const float*)d_in[0];
  const float* Wqkv  = (const float*)d_in[1];
  const float* bqkv  = (const float*)d_in[2];
  const float* Wproj = (const float*)d_in[3];
  const float* bproj = (const float*)d_in[4];
  float* out = (float*)d_out;

  // 40 MiB workspace layout; Y aliases xb (xb dead after gemm1).
  char* ws = (char*)d_ws;
  bf16* xb     = (bf16*)(ws);                        // 4096x1024 = 8 MiB
  bf16* Y      = (bf16*)(ws);                        // aliases xb
  bf16* WqkvT  = (bf16*)(ws + (8ull  << 20));        // 3072x1024 = 6 MiB
  bf16* WprojT = (bf16*)(ws + (14ull << 20));        // 1024x1024 = 2 MiB
  bf16* Qh     = (bf16*)(ws + (16ull << 20));        // [16][4096][64] = 8 MiB
  bf16* Kh     = (bf16*)(ws + (24ull << 20));        // 8 MiB
  bf16* Vt     = (bf16*)(ws + (32ull << 20));        // [16][64][4096] = 8 MiB

  f32_to_bf16<<<dim3(4096), 256, 0, stream>>>((const float4*)x, (uint64_t*)xb,
                                              TSEQ * CDIM / 4);
  transpose_f32_bf16<<<dim3(96, 32), dim3(32, 8), 0, stream>>>(
      Wqkv, WqkvT, CDIM, 3 * CDIM);
  transpose_f32_bf16<<<dim3(32, 32), dim3(32, 8), 0, stream>>>(
      Wproj, WprojT, CDIM, CDIM);
  gemm_bt<1><<<dim3(24, 32), 256, 0, stream>>>(
      xb, WqkvT, bqkv, (float*)nullptr, Qh, Kh, Vt, TSEQ, 3 * CDIM, CDIM);
  attn_kernel<<<dim3(32, 16), 256, 0, stream>>>(Qh, Kh, Vt, Y);
  gemm_bt<0><<<dim3(8, 32), 256, 0, stream>>>(
      Y, WprojT, bproj, out, (bf16*)nullptr, (bf16*)nullptr, (bf16*)nullptr,
      TSEQ, CDIM, CDIM);
}

// Round 4
// 577.001 us; speedup vs baseline: 1.3484x; 1.3484x over previous
//
#include <hip/hip_runtime.h>
#include <hip/hip_bf16.h>
#include <cstdint>
#include <cstddef>

// Problem: B=1, T=4096, C=1024, NH=16, HD=64. fp32 I/O, bf16 internal compute.
// Pipeline: convert x -> bf16; transpose+convert Wqkv/Wproj -> B^T bf16;
//           GEMM1(+bias+RoPE, scatters Q/K head-major and V transposed)
//           -> flash attention (S-transposed layout, paired q-tiles)
//           -> GEMM2(+bias) -> fp32 out.
// Workspace footprint: 40 MiB total (Y aliases xb after gemm1).
constexpr int TSEQ = 4096;
constexpr int CDIM = 1024;
constexpr int NHEAD = 16;
constexpr int HDIM = 64;

using bf16 = __hip_bfloat16;
typedef __bf16 bf16x8 __attribute__((ext_vector_type(8)));
typedef float floatx4 __attribute__((ext_vector_type(4)));

// -------- elementwise fp32 -> bf16 (4 elems/thread) --------
__global__ __launch_bounds__(256) void f32_to_bf16(
    const float4* __restrict__ in, uint64_t* __restrict__ out, int n4) {
  const int i = blockIdx.x * 256 + threadIdx.x;
  if (i < n4) {
    const float4 v = in[i];
    union { bf16 h[4]; uint64_t u; } p;
    p.h[0] = __float2bfloat16(v.x);
    p.h[1] = __float2bfloat16(v.y);
    p.h[2] = __float2bfloat16(v.z);
    p.h[3] = __float2bfloat16(v.w);
    out[i] = p.u;
  }
}

// -------- transpose + convert (fp32 -> bf16), out[c][r] = in[r][c] --------
__global__ __launch_bounds__(256) void transpose_f32_bf16(
    const float* __restrict__ in, bf16* __restrict__ out, int R, int C) {
  __shared__ float tile[32][33];
  const int c0 = blockIdx.x * 32, r0 = blockIdx.y * 32;
  const int tx = threadIdx.x, ty = threadIdx.y;  // 32 x 8
#pragma unroll
  for (int i = 0; i < 32; i += 8)
    tile[ty + i][tx] = in[(size_t)(r0 + ty + i) * C + c0 + tx];
  __syncthreads();
#pragma unroll
  for (int i = 0; i < 32; i += 8)
    out[(size_t)(c0 + ty + i) * R + r0 + tx] = __float2bfloat16(tile[tx][ty + i]);
}

// -------- GEMM: C = A(MxK,bf16) * Bt(NxK,bf16)^T + bias(fp32) --------
// MODE 0: fp32 output to Cout[M][N].
// MODE 1: qkv epilogue: cols [0,1024)=q, [1024,2048)=k -> RoPE -> Qh/Kh[h][t][64];
//         cols [2048,3072)=v -> Vt[h][d][t] (direct transposed store).
template <int MODE>
__global__ __launch_bounds__(256) void gemm_bt(
    const bf16* __restrict__ A, const bf16* __restrict__ Bt,
    const float* __restrict__ bias, float* __restrict__ Cout,
    bf16* __restrict__ Qh, bf16* __restrict__ Kh, bf16* __restrict__ Vt,
    int M, int N, int K) {
  __shared__ bf16 As[128][40];  // stride 40 -> 2-way LDS aliasing only (free)
  __shared__ bf16 Bs[128][40];
  const int tid = threadIdx.x;
  const int m0 = blockIdx.y * 128, n0 = blockIdx.x * 128;
  const int wave = tid >> 6, lane = tid & 63;
  const int l15 = lane & 15, quad = lane >> 4;
  const int wm = (wave >> 1) * 64, wn = (wave & 1) * 64;

  const floatx4 fzero = {0.f, 0.f, 0.f, 0.f};
  floatx4 acc[4][4];
#pragma unroll
  for (int mi = 0; mi < 4; mi++)
#pragma unroll
    for (int ni = 0; ni < 4; ni++) acc[mi][ni] = fzero;

  const int row0 = tid >> 2;            // 0..63
  const int colb = (tid & 3) << 3;      // 0,8,16,24

  for (int k0 = 0; k0 < K; k0 += 32) {
    __syncthreads();
    *(float4*)(&As[row0][colb]) =
        *(const float4*)(A + (size_t)(m0 + row0) * K + k0 + colb);
    *(float4*)(&As[row0 + 64][colb]) =
        *(const float4*)(A + (size_t)(m0 + row0 + 64) * K + k0 + colb);
    *(float4*)(&Bs[row0][colb]) =
        *(const float4*)(Bt + (size_t)(n0 + row0) * K + k0 + colb);
    *(float4*)(&Bs[row0 + 64][colb]) =
        *(const float4*)(Bt + (size_t)(n0 + row0 + 64) * K + k0 + colb);
    __syncthreads();

    bf16x8 a[4], b[4];
#pragma unroll
    for (int mi = 0; mi < 4; mi++)
      a[mi] = *(const bf16x8*)(&As[wm + mi * 16 + l15][quad * 8]);
#pragma unroll
    for (int ni = 0; ni < 4; ni++)
      b[ni] = *(const bf16x8*)(&Bs[wn + ni * 16 + l15][quad * 8]);
#pragma unroll
    for (int mi = 0; mi < 4; mi++)
#pragma unroll
      for (int ni = 0; ni < 4; ni++)
        acc[mi][ni] = __builtin_amdgcn_mfma_f32_16x16x32_bf16(
            a[mi], b[ni], acc[mi][ni], 0, 0, 0);
  }

  // Epilogue. C/D layout: col = lane&15, row = quad*4 + reg.
#pragma unroll
  for (int ni = 0; ni < 4; ni++) {
    const int col = n0 + wn + ni * 16 + l15;
    const float bv = bias[col];
    if (MODE == 1) {
      const int sec = col >> 10;        // 0=q 1=k 2=v (uniform per wave)
      const int cd = col & 1023;
      const int hh = cd >> 6, d = cd & 63;
      if (sec == 2) {
        // V: direct transposed store Vt[h][d][t], 4 consecutive t packed (8B)
#pragma unroll
        for (int mi = 0; mi < 4; mi++) {
          const int t0 = m0 + wm + mi * 16 + quad * 4;
          union { bf16 h[4]; uint64_t u; } p;
#pragma unroll
          for (int r = 0; r < 4; r++)
            p.h[r] = __float2bfloat16(acc[mi][ni][r] + bv);
          *(uint64_t*)(Vt + ((size_t)hh * HDIM + d) * TSEQ + t0) = p.u;
        }
      } else {
        // inv_freq[d%32] = 10000^(-2*(d%32)/64)
        const float invf =
            exp2f((float)(d & 31) * (-2.0f / 64.0f) * 13.287712379549449f);
        bf16* dst = (sec == 0) ? Qh : Kh;
#pragma unroll
        for (int mi = 0; mi < 4; mi++) {
#pragma unroll
          for (int r = 0; r < 4; r++) {
            const int row = m0 + wm + mi * 16 + quad * 4 + r;  // t
            const float v = acc[mi][ni][r] + bv;
            // pair partner (col^1) lives in lane^1
            const float partner = __shfl_xor(v, 1, 64);
            float sn, cs;
            sincosf((float)row * invf, &sn, &cs);
            const float res = v * cs + ((d & 1) ? partner : -partner) * sn;
            dst[((size_t)hh * TSEQ + row) * HDIM + d] = __float2bfloat16(res);
          }
        }
      }
    } else {
#pragma unroll
      for (int mi = 0; mi < 4; mi++) {
#pragma unroll
        for (int r = 0; r < 4; r++) {
          const int row = m0 + wm + mi * 16 + quad * 4 + r;
          Cout[(size_t)row * N + col] = acc[mi][ni][r] + bv;
        }
      }
    }
  }
}

// -------- flash attention, S-transposed --------
// grid (32, NHEAD): block p handles q-tiles (p, 63-p) of 64 rows each.
// 4 waves; wave w owns 16-row qtile slices of both: rows tile*64 + w*16 + l15.
// S^T = K(A-frag) x Q(B-frag): col=lane&15=q, row=quad*4+r=kv -> per-lane
// row-stats (2 shfls), O^T = V^T(A) x P^T(B): col=q, row=d.
__global__ __launch_bounds__(256) void attn_kernel(
    const bf16* __restrict__ Qh, const bf16* __restrict__ Kh,
    const bf16* __restrict__ Vt, bf16* __restrict__ Y) {
  const int h = blockIdx.y;
  const int p = blockIdx.x;  // pair index
  const int tile_lo = p, tile_hi = 63 - p;
  const int tid = threadIdx.x;
  const int w = tid >> 6, lane = tid & 63;
  const int l15 = lane & 15, quad = lane >> 4;
  const int q_lo = tile_lo * 64 + w * 16 + l15;
  const int q_hi = tile_hi * 64 + w * 16 + l15;
  const int nkv_lo = tile_lo + 1;  // 64-wide kv tiles for lo qtile
  const int nkv_hi = tile_hi + 1;

  const bf16* Qb = Qh + (size_t)h * TSEQ * HDIM;
  const bf16* Kb = Kh + (size_t)h * TSEQ * HDIM;
  const bf16* Vb = Vt + (size_t)h * HDIM * TSEQ;

  // per-wave P^T scratch: [q-row 0..31][kv 0..63], stride 72 bf16 (144 B)
  __shared__ bf16 Plds[4][32][72];

  // Q B-fragments: n=lane&15 (q-row), k=quad*8+j (+32*ks) over d
  bf16x8 qf[2][2];  // [qt: 0=lo 1=hi][ks]
#pragma unroll
  for (int ks = 0; ks < 2; ks++) {
    qf[0][ks] = *(const bf16x8*)(Qb + (size_t)q_lo * HDIM + ks * 32 + quad * 8);
    qf[1][ks] = *(const bf16x8*)(Qb + (size_t)q_hi * HDIM + ks * 32 + quad * 8);
  }

  const floatx4 fzero = {0.f, 0.f, 0.f, 0.f};
  floatx4 o[2][4];  // [qt][dt]: O^T, col=q(l15), row=d=dt*16+quad*4+r
  float m_i[2] = {-1e30f, -1e30f}, l_i[2] = {0.f, 0.f};
#pragma unroll
  for (int qt = 0; qt < 2; qt++)
#pragma unroll
    for (int dt = 0; dt < 4; dt++) o[qt][dt] = fzero;

  const float sc = 0.125f * 1.4426950408889634f;  // 1/sqrt(64) * log2(e)

  // softmax for one qtile's S^T column (16 kv values in s[kt][r])
  auto softmax_tile = [&](floatx4* s, int qrow, bool maskit, int kv0, int qt) {
#pragma unroll
    for (int kt = 0; kt < 4; kt++) {
#pragma unroll
      for (int r = 0; r < 4; r++) {
        const float v = s[kt][r] * sc;
        if (maskit) {
          const int kv = kv0 + kt * 16 + quad * 4 + r;
          s[kt][r] = (kv <= qrow) ? v : -1e30f;
        } else {
          s[kt][r] = v;
        }
      }
    }
    float mx = -1e30f;
#pragma unroll
    for (int kt = 0; kt < 4; kt++)
#pragma unroll
      for (int r = 0; r < 4; r++) mx = fmaxf(mx, s[kt][r]);
    mx = fmaxf(mx, __shfl_xor(mx, 16, 64));
    mx = fmaxf(mx, __shfl_xor(mx, 32, 64));
    const float mnew = fmaxf(m_i[qt], mx);
    const float alpha = exp2f(m_i[qt] - mnew);
    m_i[qt] = mnew;
    float rsum = 0.f;
#pragma unroll
    for (int kt = 0; kt < 4; kt++) {
#pragma unroll
      for (int r = 0; r < 4; r++) {
        const float pv = exp2f(s[kt][r] - mnew);
        s[kt][r] = pv;
        rsum += pv;
      }
    }
    rsum += __shfl_xor(rsum, 16, 64);
    rsum += __shfl_xor(rsum, 32, 64);
    l_i[qt] = l_i[qt] * alpha + rsum;
#pragma unroll
    for (int dt = 0; dt < 4; dt++) o[qt][dt] *= alpha;
    // pack P^T to LDS: row=qt*16+l15, col=kt*16+quad*4 (+r), 4 bf16 = b64
#pragma unroll
    for (int kt = 0; kt < 4; kt++) {
      union { bf16 hh[4]; uint64_t u; } pk;
#pragma unroll
      for (int r = 0; r < 4; r++) pk.hh[r] = __float2bfloat16(s[kt][r]);
      *(uint64_t*)(&Plds[w][qt * 16 + l15][kt * 16 + quad * 4]) = pk.u;
    }
  };

  for (int kb = 0; kb < nkv_hi; kb++) {
    const int kv0 = kb * 64;
    const bool lo_on = (kb < nkv_lo);

    // K A-fragments: m=lane&15 (kv), k=quad*8+j over d
    bf16x8 kf[4][2];
#pragma unroll
    for (int kt = 0; kt < 4; kt++)
#pragma unroll
      for (int ks = 0; ks < 2; ks++)
        kf[kt][ks] = *(const bf16x8*)(Kb +
            (size_t)(kv0 + kt * 16 + l15) * HDIM + ks * 32 + quad * 8);
    // V A-fragments (prefetch; used after softmax): m=d, k over kv
    bf16x8 vf[4][2];
#pragma unroll
    for (int dt = 0; dt < 4; dt++)
#pragma unroll
      for (int ks = 0; ks < 2; ks++)
        vf[dt][ks] = *(const bf16x8*)(Vb +
            (size_t)(dt * 16 + l15) * TSEQ + kv0 + ks * 32 + quad * 8);

    floatx4 sh[4], sl[4];
#pragma unroll
    for (int kt = 0; kt < 4; kt++) { sh[kt] = fzero; sl[kt] = fzero; }
#pragma unroll
    for (int kt = 0; kt < 4; kt++)
#pragma unroll
      for (int ks = 0; ks < 2; ks++)
        sh[kt] = __builtin_amdgcn_mfma_f32_16x16x32_bf16(
            kf[kt][ks], qf[1][ks], sh[kt], 0, 0, 0);
    if (lo_on) {
#pragma unroll
      for (int kt = 0; kt < 4; kt++)
#pragma unroll
        for (int ks = 0; ks < 2; ks++)
          sl[kt] = __builtin_amdgcn_mfma_f32_16x16x32_bf16(
              kf[kt][ks], qf[0][ks], sl[kt], 0, 0, 0);
    }

    softmax_tile(sh, q_hi, kb == nkv_hi - 1, kv0, 1);
    if (lo_on) softmax_tile(sl, q_lo, kb == nkv_lo - 1, kv0, 0);
    __asm__ __volatile__("" ::: "memory");  // order LDS pack before reads

    // P^T B-fragments: n=q(l15), k=kv=ks*32+quad*8..+7
    bf16x8 ph[2];
#pragma unroll
    for (int ks = 0; ks < 2; ks++)
      ph[ks] = *(const bf16x8*)(&Plds[w][16 + l15][ks * 32 + quad * 8]);
#pragma unroll
    for (int dt = 0; dt < 4; dt++)
#pragma unroll
      for (int ks = 0; ks < 2; ks++)
        o[1][dt] = __builtin_amdgcn_mfma_f32_16x16x32_bf16(
            vf[dt][ks], ph[ks], o[1][dt], 0, 0, 0);
    if (lo_on) {
      bf16x8 pl[2];
#pragma unroll
      for (int ks = 0; ks < 2; ks++)
        pl[ks] = *(const bf16x8*)(&Plds[w][l15][ks * 32 + quad * 8]);
#pragma unroll
      for (int dt = 0; dt < 4; dt++)
#pragma unroll
        for (int ks = 0; ks < 2; ks++)
          o[0][dt] = __builtin_amdgcn_mfma_f32_16x16x32_bf16(
              vf[dt][ks], pl[ks], o[0][dt], 0, 0, 0);
    }
  }

  // epilogue: O^T col=q(l15), row=d=dt*16+quad*4+r; write Y[q][h*64+d]
#pragma unroll
  for (int qt = 0; qt < 2; qt++) {
    const int q = (qt == 0) ? q_lo : q_hi;
    const float inv = 1.0f / l_i[qt];
#pragma unroll
    for (int dt = 0; dt < 4; dt++) {
      union { bf16 hh[4]; uint64_t u; } pk;
#pragma unroll
      for (int r = 0; r < 4; r++)
        pk.hh[r] = __float2bfloat16(o[qt][dt][r] * inv);
      *(uint64_t*)(Y + (size_t)q * CDIM + h * HDIM + dt * 16 + quad * 4) = pk.u;
    }
  }
}

extern "C" void kernel_launch(void* const* d_in, const int* in_sizes, int n_in,
                              void* d_out, int out_size, void* d_ws,
                              size_t ws_size, hipStream_t stream) {
  const float* x     = (const float*)d_in[0];
  const float* Wqkv  = (const float*)d_in[1];
  const float* bqkv  = (const float*)d_in[2];
  const float* Wproj = (const float*)d_in[3];
  const float* bproj = (const float*)d_in[4];
  float* out = (float*)d_out;

  // 40 MiB workspace layout; Y aliases xb (xb dead after gemm1).
  char* ws = (char*)d_ws;
  bf16* xb     = (bf16*)(ws);                        // 4096x1024 = 8 MiB
  bf16* Y      = (bf16*)(ws);                        // aliases xb
  bf16* WqkvT  = (bf16*)(ws + (8ull  << 20));        // 3072x1024 = 6 MiB
  bf16* WprojT = (bf16*)(ws + (14ull << 20));        // 1024x1024 = 2 MiB
  bf16* Qh     = (bf16*)(ws + (16ull << 20));        // [16][4096][64] = 8 MiB
  bf16* Kh     = (bf16*)(ws + (24ull << 20));        // 8 MiB
  bf16* Vt     = (bf16*)(ws + (32ull << 20));        // [16][64][4096] = 8 MiB

  f32_to_bf16<<<dim3(4096), 256, 0, stream>>>((const float4*)x, (uint64_t*)xb,
                                              TSEQ * CDIM / 4);
  transpose_f32_bf16<<<dim3(96, 32), dim3(32, 8), 0, stream>>>(
      Wqkv, WqkvT, CDIM, 3 * CDIM);
  transpose_f32_bf16<<<dim3(32, 32), dim3(32, 8), 0, stream>>>(
      Wproj, WprojT, CDIM, CDIM);
  gemm_bt<1><<<dim3(24, 32), 256, 0, stream>>>(
      xb, WqkvT, bqkv, (float*)nullptr, Qh, Kh, Vt, TSEQ, 3 * CDIM, CDIM);
  attn_kernel<<<dim3(32, 16), 256, 0, stream>>>(Qh, Kh, Vt, Y);
  gemm_bt<0><<<dim3(8, 32), 256, 0, stream>>>(
      Y, WprojT, bproj, out, (bf16*)nullptr, (bf16*)nullptr, (bf16*)nullptr,
      TSEQ, CDIM, CDIM);
}

// Round 6
// 397.564 us; speedup vs baseline: 1.9570x; 1.4513x over previous
//
#include <hip/hip_runtime.h>
#include <hip/hip_bf16.h>
#include <cstdint>
#include <cstddef>

// Problem: B=1, T=4096, C=1024, NH=16, HD=64. fp32 I/O, bf16 internal compute.
// Pipeline: convert x -> bf16; transpose+convert Wqkv -> B^T bf16; rope table;
//           GEMM1(+bias+RoPE, vectorized LDS-transposed epilogue stores)
//           -> transpose Wproj (overwrites rope table region)
//           -> flash attention (S-transposed layout, paired q-tiles)
//           -> GEMM2(+bias) -> fp32 out.
// Workspace footprint: 40 MiB total (Y aliases xb; rope table aliases WprojT).
constexpr int TSEQ = 4096;
constexpr int CDIM = 1024;
constexpr int NHEAD = 16;
constexpr int HDIM = 64;

using bf16 = __hip_bfloat16;
typedef __bf16 bf16x8 __attribute__((ext_vector_type(8)));
typedef float floatx4 __attribute__((ext_vector_type(4)));

// -------- elementwise fp32 -> bf16 (4 elems/thread) --------
__global__ __launch_bounds__(256) void f32_to_bf16(
    const float4* __restrict__ in, uint64_t* __restrict__ out, int n4) {
  const int i = blockIdx.x * 256 + threadIdx.x;
  if (i < n4) {
    const float4 v = in[i];
    union { bf16 h[4]; uint64_t u; } p;
    p.h[0] = __float2bfloat16(v.x);
    p.h[1] = __float2bfloat16(v.y);
    p.h[2] = __float2bfloat16(v.z);
    p.h[3] = __float2bfloat16(v.w);
    out[i] = p.u;
  }
}

// -------- rope table: tab[t][0..31]=cos(t*invf_j), tab[t][32..63]=sin --------
__global__ __launch_bounds__(256) void rope_table(float* __restrict__ tab) {
  const int i = blockIdx.x * 256 + threadIdx.x;  // over TSEQ*32
  const int t = i >> 5, j = i & 31;
  const float invf = exp2f((float)j * (-2.0f / 64.0f) * 13.287712379549449f);
  float sn, cs;
  sincosf((float)t * invf, &sn, &cs);
  tab[t * 64 + j] = cs;
  tab[t * 64 + 32 + j] = sn;
}

// -------- transpose + convert (fp32 -> bf16), out[c][r] = in[r][c] --------
__global__ __launch_bounds__(256) void transpose_f32_bf16(
    const float* __restrict__ in, bf16* __restrict__ out, int R, int C) {
  __shared__ float tile[32][33];
  const int c0 = blockIdx.x * 32, r0 = blockIdx.y * 32;
  const int tx = threadIdx.x, ty = threadIdx.y;  // 32 x 8
#pragma unroll
  for (int i = 0; i < 32; i += 8)
    tile[ty + i][tx] = in[(size_t)(r0 + ty + i) * C + c0 + tx];
  __syncthreads();
#pragma unroll
  for (int i = 0; i < 32; i += 8)
    out[(size_t)(c0 + ty + i) * R + r0 + tx] = __float2bfloat16(tile[tx][ty + i]);
}

// -------- GEMM: C = A(MxK,bf16) * Bt(NxK,bf16)^T + bias(fp32) --------
// MODE 0: fp32 output to Cout[M][N] (vectorized via LDS transpose scratch).
// MODE 1: qkv epilogue: cols [0,1024)=q, [1024,2048)=k -> RoPE (table) ->
//         Qh/Kh[h][t][64]; cols [2048,3072)=v -> Vt[h][d][t]. All stores are
//         LDS-staged then 16B/lane contiguous (1KB per instruction).
template <int MODE>
__global__ __launch_bounds__(256) void gemm_bt(
    const bf16* __restrict__ A, const bf16* __restrict__ Bt,
    const float* __restrict__ bias, const float* __restrict__ tab,
    float* __restrict__ Cout,
    bf16* __restrict__ Qh, bf16* __restrict__ Kh, bf16* __restrict__ Vt,
    int M, int N, int K) {
  // 36.9KB shared: sized for the epilogue scratch (4 waves x 64x72 bf16 =
  // 36864B); the K-loop staging (2 x 128 x 40 bf16 = 20480B) uses the front.
  __shared__ __align__(16) bf16 smem[4 * 64 * 72];
  bf16* As = smem;              // As[r][c] = smem[r*40+c]
  bf16* Bs = smem + 128 * 40;
  const int tid = threadIdx.x;
  const int m0 = blockIdx.y * 128, n0 = blockIdx.x * 128;
  const int wave = tid >> 6, lane = tid & 63;
  const int l15 = lane & 15, quad = lane >> 4;
  const int wm = (wave >> 1) * 64, wn = (wave & 1) * 64;

  const floatx4 fzero = {0.f, 0.f, 0.f, 0.f};
  floatx4 acc[4][4];
#pragma unroll
  for (int mi = 0; mi < 4; mi++)
#pragma unroll
    for (int ni = 0; ni < 4; ni++) acc[mi][ni] = fzero;

  const int row0 = tid >> 2;            // 0..63
  const int colb = (tid & 3) << 3;      // 0,8,16,24

  for (int k0 = 0; k0 < K; k0 += 32) {
    __syncthreads();
    *(float4*)(As + row0 * 40 + colb) =
        *(const float4*)(A + (size_t)(m0 + row0) * K + k0 + colb);
    *(float4*)(As + (row0 + 64) * 40 + colb) =
        *(const float4*)(A + (size_t)(m0 + row0 + 64) * K + k0 + colb);
    *(float4*)(Bs + row0 * 40 + colb) =
        *(const float4*)(Bt + (size_t)(n0 + row0) * K + k0 + colb);
    *(float4*)(Bs + (row0 + 64) * 40 + colb) =
        *(const float4*)(Bt + (size_t)(n0 + row0 + 64) * K + k0 + colb);
    __syncthreads();

    bf16x8 a[4], b[4];
#pragma unroll
    for (int mi = 0; mi < 4; mi++)
      a[mi] = *(const bf16x8*)(As + (wm + mi * 16 + l15) * 40 + quad * 8);
#pragma unroll
    for (int ni = 0; ni < 4; ni++)
      b[ni] = *(const bf16x8*)(Bs + (wn + ni * 16 + l15) * 40 + quad * 8);
#pragma unroll
    for (int mi = 0; mi < 4; mi++)
#pragma unroll
      for (int ni = 0; ni < 4; ni++)
        acc[mi][ni] = __builtin_amdgcn_mfma_f32_16x16x32_bf16(
            a[mi], b[ni], acc[mi][ni], 0, 0, 0);
  }

  // ---- Epilogue. C/D layout: col = lane&15, row = quad*4 + reg. ----
  __syncthreads();  // all waves done with As/Bs; reuse as scratch

  if (MODE == 1) {
    bf16* ep = smem + (size_t)wave * (64 * 72);  // 4 x 9216B = 36864B
    const int cbase = n0 + wn;                   // multiple of 64
    const int sec = cbase >> 10;                 // 0=q 1=k 2=v (wave-uniform)
    const int hh = (cbase & 1023) >> 6;          // head (uniform per wave)
    if (sec == 2) {
      // stage V^T: ep[d][t_rel], stride 72
#pragma unroll
      for (int ni = 0; ni < 4; ni++) {
        const int d = ni * 16 + l15;
        const float bv = bias[cbase + d];
#pragma unroll
        for (int mi = 0; mi < 4; mi++)
#pragma unroll
          for (int r = 0; r < 4; r++)
            ep[(size_t)d * 72 + mi * 16 + quad * 4 + r] =
                __float2bfloat16(acc[mi][ni][r] + bv);
      }
      __asm__ __volatile__("" ::: "memory");  // same-wave DS order
#pragma unroll
      for (int it = 0; it < 8; it++) {
        const int dr = it * 8 + (lane >> 3);
        const int t8 = (lane & 7) * 8;
        const bf16x8 vv = *(const bf16x8*)(ep + (size_t)dr * 72 + t8);
        *(bf16x8*)(Vt + ((size_t)hh * HDIM + dr) * TSEQ + m0 + wm + t8) = vv;
      }
    } else {
      bf16* dst = (sec == 0) ? Qh : Kh;
      // stage RoPE'd rows: ep[t_rel][c], stride 72
#pragma unroll
      for (int ni = 0; ni < 4; ni++) {
        const int c = ni * 16 + l15;  // == d, 0..63
        const float bv = bias[cbase + c];
        const int j = c & 31;
#pragma unroll
        for (int mi = 0; mi < 4; mi++) {
#pragma unroll
          for (int r = 0; r < 4; r++) {
            const int t = m0 + wm + mi * 16 + quad * 4 + r;
            const float v = acc[mi][ni][r] + bv;
            const float partner = __shfl_xor(v, 1, 64);  // col^1 in lane^1
            const float cs = tab[t * 64 + j];
            const float sn = tab[t * 64 + 32 + j];
            const float res = v * cs + ((c & 1) ? partner : -partner) * sn;
            ep[(size_t)(mi * 16 + quad * 4 + r) * 72 + c] =
                __float2bfloat16(res);
          }
        }
      }
      __asm__ __volatile__("" ::: "memory");
#pragma unroll
      for (int it = 0; it < 8; it++) {
        const int row = it * 8 + (lane >> 3);
        const int c8 = (lane & 7) * 8;
        const bf16x8 vv = *(const bf16x8*)(ep + (size_t)row * 72 + c8);
        *(bf16x8*)(dst + ((size_t)hh * TSEQ + m0 + wm + row) * HDIM + c8) = vv;
      }
    }
  } else {
    float* ep32 = (float*)smem + (size_t)wave * (32 * 68);  // 4 x 8704B
    float bvv[4];
#pragma unroll
    for (int ni = 0; ni < 4; ni++) bvv[ni] = bias[n0 + wn + ni * 16 + l15];
#pragma unroll
    for (int half = 0; half < 2; half++) {
      if (half) __asm__ __volatile__("" ::: "memory");
#pragma unroll
      for (int ni = 0; ni < 4; ni++)
#pragma unroll
        for (int mi2 = 0; mi2 < 2; mi2++)
#pragma unroll
          for (int r = 0; r < 4; r++)
            ep32[(size_t)(mi2 * 16 + quad * 4 + r) * 68 + ni * 16 + l15] =
                acc[half * 2 + mi2][ni][r] + bvv[ni];
      __asm__ __volatile__("" ::: "memory");
#pragma unroll
      for (int it = 0; it < 8; it++) {
        const int row = it * 4 + (lane >> 4);
        const float4 vv = *(const float4*)(ep32 + (size_t)row * 68 + l15 * 4);
        *(float4*)(Cout + (size_t)(m0 + wm + half * 32 + row) * N + n0 + wn +
                   l15 * 4) = vv;
      }
    }
  }
}

// -------- flash attention, S-transposed --------
// grid (32, NHEAD): block p handles q-tiles (p, 63-p) of 64 rows each.
// 4 waves; wave w owns 16-row qtile slices of both: rows tile*64 + w*16 + l15.
// S^T = K(A-frag) x Q(B-frag): col=lane&15=q, row=quad*4+r=kv -> per-lane
// row-stats (2 shfls), O^T = V^T(A) x P^T(B): col=q, row=d.
__global__ __launch_bounds__(256) void attn_kernel(
    const bf16* __restrict__ Qh, const bf16* __restrict__ Kh,
    const bf16* __restrict__ Vt, bf16* __restrict__ Y) {
  const int h = blockIdx.y;
  const int p = blockIdx.x;  // pair index
  const int tile_lo = p, tile_hi = 63 - p;
  const int tid = threadIdx.x;
  const int w = tid >> 6, lane = tid & 63;
  const int l15 = lane & 15, quad = lane >> 4;
  const int q_lo = tile_lo * 64 + w * 16 + l15;
  const int q_hi = tile_hi * 64 + w * 16 + l15;
  const int nkv_lo = tile_lo + 1;  // 64-wide kv tiles for lo qtile
  const int nkv_hi = tile_hi + 1;

  const bf16* Qb = Qh + (size_t)h * TSEQ * HDIM;
  const bf16* Kb = Kh + (size_t)h * TSEQ * HDIM;
  const bf16* Vb = Vt + (size_t)h * HDIM * TSEQ;

  // per-wave P^T scratch: [q-row 0..31][kv 0..63], stride 72 bf16 (144 B)
  __shared__ bf16 Plds[4][32][72];

  // Q B-fragments: n=lane&15 (q-row), k=quad*8+j (+32*ks) over d
  bf16x8 qf[2][2];  // [qt: 0=lo 1=hi][ks]
#pragma unroll
  for (int ks = 0; ks < 2; ks++) {
    qf[0][ks] = *(const bf16x8*)(Qb + (size_t)q_lo * HDIM + ks * 32 + quad * 8);
    qf[1][ks] = *(const bf16x8*)(Qb + (size_t)q_hi * HDIM + ks * 32 + quad * 8);
  }

  const floatx4 fzero = {0.f, 0.f, 0.f, 0.f};
  floatx4 o[2][4];  // [qt][dt]: O^T, col=q(l15), row=d=dt*16+quad*4+r
  float m_i[2] = {-1e30f, -1e30f}, l_i[2] = {0.f, 0.f};
#pragma unroll
  for (int qt = 0; qt < 2; qt++)
#pragma unroll
    for (int dt = 0; dt < 4; dt++) o[qt][dt] = fzero;

  const float sc = 0.125f * 1.4426950408889634f;  // 1/sqrt(64) * log2(e)

  // softmax for one qtile's S^T column (16 kv values in s[kt][r])
  auto softmax_tile = [&](floatx4* s, int qrow, bool maskit, int kv0, int qt) {
#pragma unroll
    for (int kt = 0; kt < 4; kt++) {
#pragma unroll
      for (int r = 0; r < 4; r++) {
        const float v = s[kt][r] * sc;
        if (maskit) {
          const int kv = kv0 + kt * 16 + quad * 4 + r;
          s[kt][r] = (kv <= qrow) ? v : -1e30f;
        } else {
          s[kt][r] = v;
        }
      }
    }
    float mx = -1e30f;
#pragma unroll
    for (int kt = 0; kt < 4; kt++)
#pragma unroll
      for (int r = 0; r < 4; r++) mx = fmaxf(mx, s[kt][r]);
    mx = fmaxf(mx, __shfl_xor(mx, 16, 64));
    mx = fmaxf(mx, __shfl_xor(mx, 32, 64));
    const float mnew = fmaxf(m_i[qt], mx);
    const float alpha = exp2f(m_i[qt] - mnew);
    m_i[qt] = mnew;
    float rsum = 0.f;
#pragma unroll
    for (int kt = 0; kt < 4; kt++) {
#pragma unroll
      for (int r = 0; r < 4; r++) {
        const float pv = exp2f(s[kt][r] - mnew);
        s[kt][r] = pv;
        rsum += pv;
      }
    }
    rsum += __shfl_xor(rsum, 16, 64);
    rsum += __shfl_xor(rsum, 32, 64);
    l_i[qt] = l_i[qt] * alpha + rsum;
#pragma unroll
    for (int dt = 0; dt < 4; dt++) o[qt][dt] *= alpha;
    // pack P^T to LDS: row=qt*16+l15, col=kt*16+quad*4 (+r), 4 bf16 = b64
#pragma unroll
    for (int kt = 0; kt < 4; kt++) {
      union { bf16 hh[4]; uint64_t u; } pk;
#pragma unroll
      for (int r = 0; r < 4; r++) pk.hh[r] = __float2bfloat16(s[kt][r]);
      *(uint64_t*)(&Plds[w][qt * 16 + l15][kt * 16 + quad * 4]) = pk.u;
    }
  };

  for (int kb = 0; kb < nkv_hi; kb++) {
    const int kv0 = kb * 64;
    const bool lo_on = (kb < nkv_lo);

    // K A-fragments: m=lane&15 (kv), k=quad*8+j over d
    bf16x8 kf[4][2];
#pragma unroll
    for (int kt = 0; kt < 4; kt++)
#pragma unroll
      for (int ks = 0; ks < 2; ks++)
        kf[kt][ks] = *(const bf16x8*)(Kb +
            (size_t)(kv0 + kt * 16 + l15) * HDIM + ks * 32 + quad * 8);
    // V A-fragments (prefetch; used after softmax): m=d, k over kv
    bf16x8 vf[4][2];
#pragma unroll
    for (int dt = 0; dt < 4; dt++)
#pragma unroll
      for (int ks = 0; ks < 2; ks++)
        vf[dt][ks] = *(const bf16x8*)(Vb +
            (size_t)(dt * 16 + l15) * TSEQ + kv0 + ks * 32 + quad * 8);

    floatx4 sh[4], sl[4];
#pragma unroll
    for (int kt = 0; kt < 4; kt++) { sh[kt] = fzero; sl[kt] = fzero; }
#pragma unroll
    for (int kt = 0; kt < 4; kt++)
#pragma unroll
      for (int ks = 0; ks < 2; ks++)
        sh[kt] = __builtin_amdgcn_mfma_f32_16x16x32_bf16(
            kf[kt][ks], qf[1][ks], sh[kt], 0, 0, 0);
    if (lo_on) {
#pragma unroll
      for (int kt = 0; kt < 4; kt++)
#pragma unroll
        for (int ks = 0; ks < 2; ks++)
          sl[kt] = __builtin_amdgcn_mfma_f32_16x16x32_bf16(
              kf[kt][ks], qf[0][ks], sl[kt], 0, 0, 0);
    }

    softmax_tile(sh, q_hi, kb == nkv_hi - 1, kv0, 1);
    if (lo_on) softmax_tile(sl, q_lo, kb == nkv_lo - 1, kv0, 0);
    __asm__ __volatile__("" ::: "memory");  // order LDS pack before reads

    // P^T B-fragments: n=q(l15), k=kv=ks*32+quad*8..+7
    bf16x8 ph[2];
#pragma unroll
    for (int ks = 0; ks < 2; ks++)
      ph[ks] = *(const bf16x8*)(&Plds[w][16 + l15][ks * 32 + quad * 8]);
#pragma unroll
    for (int dt = 0; dt < 4; dt++)
#pragma unroll
      for (int ks = 0; ks < 2; ks++)
        o[1][dt] = __builtin_amdgcn_mfma_f32_16x16x32_bf16(
            vf[dt][ks], ph[ks], o[1][dt], 0, 0, 0);
    if (lo_on) {
      bf16x8 pl[2];
#pragma unroll
      for (int ks = 0; ks < 2; ks++)
        pl[ks] = *(const bf16x8*)(&Plds[w][l15][ks * 32 + quad * 8]);
#pragma unroll
      for (int dt = 0; dt < 4; dt++)
#pragma unroll
        for (int ks = 0; ks < 2; ks++)
          o[0][dt] = __builtin_amdgcn_mfma_f32_16x16x32_bf16(
              vf[dt][ks], pl[ks], o[0][dt], 0, 0, 0);
    }
  }

  // epilogue: O^T col=q(l15), row=d=dt*16+quad*4+r; write Y[q][h*64+d]
#pragma unroll
  for (int qt = 0; qt < 2; qt++) {
    const int q = (qt == 0) ? q_lo : q_hi;
    const float inv = 1.0f / l_i[qt];
#pragma unroll
    for (int dt = 0; dt < 4; dt++) {
      union { bf16 hh[4]; uint64_t u; } pk;
#pragma unroll
      for (int r = 0; r < 4; r++)
        pk.hh[r] = __float2bfloat16(o[qt][dt][r] * inv);
      *(uint64_t*)(Y + (size_t)q * CDIM + h * HDIM + dt * 16 + quad * 4) = pk.u;
    }
  }
}

extern "C" void kernel_launch(void* const* d_in, const int* in_sizes, int n_in,
                              void* d_out, int out_size, void* d_ws,
                              size_t ws_size, hipStream_t stream) {
  const float* x     = (const float*)d_in[0];
  const float* Wqkv  = (const float*)d_in[1];
  const float* bqkv  = (const float*)d_in[2];
  const float* Wproj = (const float*)d_in[3];
  const float* bproj = (const float*)d_in[4];
  float* out = (float*)d_out;

  // 40 MiB workspace layout; Y aliases xb (xb dead after gemm1);
  // rope table aliases WprojT (WprojT transposed after gemm1).
  char* ws = (char*)d_ws;
  bf16* xb     = (bf16*)(ws);                        // 4096x1024 = 8 MiB
  bf16* Y      = (bf16*)(ws);                        // aliases xb
  bf16* WqkvT  = (bf16*)(ws + (8ull  << 20));        // 3072x1024 = 6 MiB
  bf16* WprojT = (bf16*)(ws + (14ull << 20));        // 1024x1024 = 2 MiB
  float* tab   = (float*)(ws + (14ull << 20));       // 4096x64 fp32 = 1 MiB
  bf16* Qh     = (bf16*)(ws + (16ull << 20));        // [16][4096][64] = 8 MiB
  bf16* Kh     = (bf16*)(ws + (24ull << 20));        // 8 MiB
  bf16* Vt     = (bf16*)(ws + (32ull << 20));        // [16][64][4096] = 8 MiB

  f32_to_bf16<<<dim3(4096), 256, 0, stream>>>((const float4*)x, (uint64_t*)xb,
                                              TSEQ * CDIM / 4);
  transpose_f32_bf16<<<dim3(96, 32), dim3(32, 8), 0, stream>>>(
      Wqkv, WqkvT, CDIM, 3 * CDIM);
  rope_table<<<dim3(TSEQ * 32 / 256), 256, 0, stream>>>(tab);
  gemm_bt<1><<<dim3(24, 32), 256, 0, stream>>>(
      xb, WqkvT, bqkv, tab, (float*)nullptr, Qh, Kh, Vt, TSEQ, 3 * CDIM, CDIM);
  transpose_f32_bf16<<<dim3(32, 32), dim3(32, 8), 0, stream>>>(
      Wproj, WprojT, CDIM, CDIM);  // overwrites tab (dead after gemm1)
  attn_kernel<<<dim3(32, 16), 256, 0, stream>>>(Qh, Kh, Vt, Y);
  gemm_bt<0><<<dim3(8, 32), 256, 0, stream>>>(
      Y, WprojT, bproj, (float*)nullptr, out, (bf16*)nullptr, (bf16*)nullptr,
      (bf16*)nullptr, TSEQ, CDIM, CDIM);
}